// Round 9
// baseline (177.435 us; speedup 1.0000x reference)
//
#include <hip/hip_runtime.h>
#include <hip/hip_bf16.h>
#include <stdint.h>

#define B_  2
#define S_  2048
#define D_  1024
#define H_  16
#define HD_ 64

typedef __attribute__((ext_vector_type(8)))  __bf16 bf16x8;
typedef __attribute__((ext_vector_type(4)))  __bf16 bf16x4;
typedef __attribute__((ext_vector_type(2)))  __bf16 bf16x2;
typedef __attribute__((ext_vector_type(4)))  float  f32x4;
typedef __attribute__((ext_vector_type(16))) float  f32x16;
typedef __attribute__((ext_vector_type(4)))  uint32_t u32x4;

// 0.125 * log2(e): folded into Q so attention scores feed exp2 directly.
#define QSCALE 0.18033688011112042f

__device__ __forceinline__ void gload16(const void* g, void* l) {
  __builtin_amdgcn_global_load_lds(
      (__attribute__((address_space(1))) void*)(uintptr_t)g,
      (__attribute__((address_space(3))) void*)(uintptr_t)l,
      16, 0, 0);
}

// ---------------- fused prep: zero out / convert X / transpose W ----------------
__global__ __launch_bounds__(256) void prep(
    const float* __restrict__ x, const float* __restrict__ wq,
    const float* __restrict__ wk, const float* __restrict__ wv,
    __bf16* __restrict__ xb, __bf16* __restrict__ wt, float* __restrict__ out) {
  __shared__ float tile[32][33];
  const int t = threadIdx.x;
  const int bx = blockIdx.x;
  if (bx < 4096) {
    int i = bx * 256 + t;
    float4 v = ((const float4*)x)[i];
    bf16x4 o;
    o[0] = (__bf16)v.x; o[1] = (__bf16)v.y; o[2] = (__bf16)v.z; o[3] = (__bf16)v.w;
    ((bf16x4*)xb)[i] = o;
  } else if (bx < 7168) {
    int tb = bx - 4096;
    int z = tb >> 10;
    int rem = tb & 1023;
    int n0 = (rem & 31) * 32, k0 = (rem >> 5) * 32;
    const float* w = (z == 0) ? wq : (z == 1 ? wk : wv);
    __bf16* o = wt + (size_t)z * D_ * D_;
    int tx = t & 31, ty = t >> 5;
    for (int i = 0; i < 4; ++i)
      tile[ty + 8 * i][tx] = w[(size_t)(k0 + ty + 8 * i) * D_ + n0 + tx];
    __syncthreads();
    for (int i = 0; i < 4; ++i)
      o[(size_t)(n0 + ty + 8 * i) * D_ + k0 + tx] = (__bf16)tile[tx][ty + 8 * i];
  } else {
    float4* o4 = (float4*)out;
    float4 z4 = {0.f, 0.f, 0.f, 0.f};
    o4[t] = z4;
    o4[t + 256] = z4;
  }
}

// ---------------- QKV GEMM, 128x64 tile, BK=32, dbuf ----------------
// grid (my=32, nx=16, z=3) = 1536 blocks; 4 blocks/CU -> 16 waves/CU.
// XCD: linear%8 tracks my%8 -> A-panel (X rows) XCD-local.
// Wave w owns m rows [wid*32, +32); n = 64 shared.
// z=0 -> Q (pre-scaled) [B,H,S,HD]; z=1 -> K; z=2 -> V^T [B,H,HD,S]
__global__ __launch_bounds__(256, 4) void gemm_qkv(
    const __bf16* __restrict__ xb, const __bf16* __restrict__ wt,
    const float* __restrict__ bq, const float* __restrict__ bk,
    const float* __restrict__ bv, __bf16* __restrict__ qh,
    __bf16* __restrict__ kh, __bf16* __restrict__ vt) {
  constexpr int K = 1024;
  constexpr int NIT = K / 32;
  __shared__ __attribute__((aligned(16))) __bf16 lA[2][128 * 32];
  __shared__ __attribute__((aligned(16))) __bf16 lB[2][64 * 32];

  const int z = blockIdx.z;
  const __bf16* w = wt + (size_t)z * K * D_;
  const float* bias = (z == 0) ? bq : (z == 1 ? bk : bv);
  const int t = threadIdx.x;
  const int lane = t & 63;
  const int wid = t >> 6;
  const int quad = lane >> 4;
  const int col = lane & 15;
  const int m0 = blockIdx.x * 128;
  const int n0 = blockIdx.y * 64;

  const int sr0 = t >> 2;
  const int gc = (t & 3) ^ ((t >> 2) & 3);

  auto stage = [&](int kt, int buf) {
    gload16(xb + (size_t)(m0 + sr0) * K + kt * 32 + gc * 8,
            (char*)&lA[buf][0] + t * 16);
    gload16(xb + (size_t)(m0 + 64 + sr0) * K + kt * 32 + gc * 8,
            (char*)&lA[buf][0] + 4096 + t * 16);
    gload16(w + (size_t)(n0 + sr0) * K + kt * 32 + gc * 8,
            (char*)&lB[buf][0] + t * 16);
  };

  f32x4 acc[4][2] = {};  // z<2: [n-tile][m-tile] ; z=2: acc[j][i] used as [n][m] too

  stage(0, 0);

  if (z < 2) {
    // D = Wt_tile * X_tile^T : rows=n (64), cols=m (wave's 32)
    for (int kt = 0; kt < NIT; ++kt) {
      const int cur = kt & 1;
      __syncthreads();
      if (kt + 1 < NIT) stage(kt + 1, cur ^ 1);
      bf16x8 fw[4], fx[2];
      for (int i = 0; i < 4; ++i) {
        int n = i * 16 + col;
        int sl = quad ^ (n & 3);
        fw[i] = *(const bf16x8*)((const char*)&lB[cur][0] + n * 64 + sl * 16);
      }
      for (int j = 0; j < 2; ++j) {
        int m = wid * 32 + j * 16 + col;
        int sl = quad ^ (m & 3);
        fx[j] = *(const bf16x8*)((const char*)&lA[cur][0] + m * 64 + sl * 16);
      }
      for (int i = 0; i < 4; ++i)
        for (int j = 0; j < 2; ++j)
          acc[i][j] = __builtin_amdgcn_mfma_f32_16x16x32_bf16(
              fw[i], fx[j], acc[i][j], 0, 0, 0);
    }
    const float scale = (z == 0) ? QSCALE : 1.0f;
    __bf16* dst = (z == 0) ? qh : kh;
    for (int i = 0; i < 4; ++i) {
      int gnb = n0 + i * 16 + quad * 4;  // 4-aligned hd base
      float4 bi = *(const float4*)(bias + gnb);
      int h = gnb >> 6, hd = gnb & 63;
      for (int j = 0; j < 2; ++j) {
        int gm = m0 + wid * 32 + j * 16 + col;
        int b = gm >> 11, s = gm & 2047;
        bf16x4 pk;
        pk[0] = (__bf16)((acc[i][j][0] + bi.x) * scale);
        pk[1] = (__bf16)((acc[i][j][1] + bi.y) * scale);
        pk[2] = (__bf16)((acc[i][j][2] + bi.z) * scale);
        pk[3] = (__bf16)((acc[i][j][3] + bi.w) * scale);
        *(bf16x4*)(dst + ((size_t)(b * H_ + h) * S_ + s) * HD_ + hd) = pk;
      }
    }
  } else {
    // D = X_tile * Wt_tile^T : rows=m (wave's 32), cols=n (64)
    for (int kt = 0; kt < NIT; ++kt) {
      const int cur = kt & 1;
      __syncthreads();
      if (kt + 1 < NIT) stage(kt + 1, cur ^ 1);
      bf16x8 fx[2], fw[4];
      for (int i = 0; i < 2; ++i) {
        int m = wid * 32 + i * 16 + col;
        int sl = quad ^ (m & 3);
        fx[i] = *(const bf16x8*)((const char*)&lA[cur][0] + m * 64 + sl * 16);
      }
      for (int j = 0; j < 4; ++j) {
        int n = j * 16 + col;
        int sl = quad ^ (n & 3);
        fw[j] = *(const bf16x8*)((const char*)&lB[cur][0] + n * 64 + sl * 16);
      }
      for (int j = 0; j < 4; ++j)
        for (int i = 0; i < 2; ++i)
          acc[j][i] = __builtin_amdgcn_mfma_f32_16x16x32_bf16(
              fx[i], fw[j], acc[j][i], 0, 0, 0);
    }
    for (int i = 0; i < 2; ++i) {
      int gmb = m0 + wid * 32 + i * 16 + quad * 4;  // 4-aligned s base
      int b = gmb >> 11, s = gmb & 2047;
      for (int j = 0; j < 4; ++j) {
        int gn = n0 + j * 16 + col;
        int h = gn >> 6, hd = gn & 63;
        float bi = bias[gn];
        bf16x4 pk;
        pk[0] = (__bf16)(acc[j][i][0] + bi);
        pk[1] = (__bf16)(acc[j][i][1] + bi);
        pk[2] = (__bf16)(acc[j][i][2] + bi);
        pk[3] = (__bf16)(acc[j][i][3] + bi);
        *(bf16x4*)(vt + ((size_t)(b * H_ + h) * HD_ + hd) * S_ + s) = pk;
      }
    }
  }
}

// ---------------- attention phase 1, double-buffered K-tile=64 ----------------
// grid (bh=32, qblk=16, kc=2) = 1024 blocks = 4/CU; XCD = bh%8.
// Single barrier/iter: barrier -> prefetch kt+1 (other buf) -> compute kt.
// PV via K=16 MFMA + one cross-half shfl (R7 path — full-rate instructions).
__global__ __launch_bounds__(256, 4) void attn1(
    const __bf16* __restrict__ qh, const __bf16* __restrict__ kh,
    const __bf16* __restrict__ vt, __bf16* __restrict__ po,
    float* __restrict__ pl) {
  __shared__ __attribute__((aligned(16))) __bf16 lK[2][64 * 64];  // [sk][hd] swz
  __shared__ __attribute__((aligned(16))) __bf16 lV[2][64 * 64];  // [hd][sk] swz

  const int t = threadIdx.x;
  const int lane = t & 63;
  const int half = lane >> 5;
  const int q31 = lane & 31;
  const int bh = blockIdx.x;
  const int kc = blockIdx.z;
  const int q0w = blockIdx.y * 128 + (t >> 6) * 32;

  const __bf16* qbase = qh + (size_t)bh * S_ * HD_;
  const __bf16* kbase = kh + (size_t)bh * S_ * HD_;
  const __bf16* vbase = vt + (size_t)bh * HD_ * S_;

  // Q as B-frags: B[n=q=lane&31][k=16ks+8*half+j]
  bf16x8 aq[4];
  for (int ks = 0; ks < 4; ++ks)
    aq[ks] = *(const bf16x8*)(qbase + (size_t)(q0w + q31) * HD_ + ks * 16 + half * 8);

  f32x16 o[2] = {};
  float lsum = 0.f;

  const int srow = t >> 3;                  // 0..31
  const int sgc = (t & 7) ^ (srow & 7);     // swizzled global chunk

  auto stage = [&](int kt, int buf) {
    gload16(kbase + (size_t)(kt * 64 + srow) * HD_ + sgc * 8,
            (char*)&lK[buf][0] + t * 16);
    gload16(kbase + (size_t)(kt * 64 + 32 + srow) * HD_ + sgc * 8,
            (char*)&lK[buf][0] + 4096 + t * 16);
    gload16(vbase + (size_t)srow * S_ + kt * 64 + sgc * 8,
            (char*)&lV[buf][0] + t * 16);
    gload16(vbase + (size_t)(32 + srow) * S_ + kt * 64 + sgc * 8,
            (char*)&lV[buf][0] + 4096 + t * 16);
  };

  stage(kc * 16, 0);

  for (int kt0 = 0; kt0 < 16; ++kt0) {
    const int cur = kt0 & 1;
    __syncthreads();  // drains vmcnt: buf[cur] staged; all done reading buf[cur^1]
    if (kt0 + 1 < 16) stage(kc * 16 + kt0 + 1, cur ^ 1);

    for (int st = 0; st < 2; ++st) {
      // S^T tile [sk 32][q 32] = K_tile · Q^T
      f32x16 sc = {};
      const int row = st * 32 + q31;
      for (int ks = 0; ks < 4; ++ks) {
        int pos = (2 * ks + half) ^ (row & 7);
        bf16x8 fk = *(const bf16x8*)((const char*)&lK[cur][0] + row * 128 + pos * 16);
        sc = __builtin_amdgcn_mfma_f32_32x32x16_bf16(fk, aq[ks], sc, 0, 0, 0);
      }

      // exp2 + lsum + pack pairs via v_perm (round-half-up)
      uint32_t pk[8];
      for (int p = 0; p < 8; ++p) {
        float ea = __builtin_amdgcn_exp2f(sc[2 * p]);
        float eb = __builtin_amdgcn_exp2f(sc[2 * p + 1]);
        lsum += ea;
        lsum += eb;
        uint32_t au = __builtin_bit_cast(uint32_t, ea) + 0x8000u;
        uint32_t bu = __builtin_bit_cast(uint32_t, eb) + 0x8000u;
        pk[p] = __builtin_amdgcn_perm(bu, au, 0x07060302u);
      }

      // cross-half exchange -> K=16 B-frags
      uint32_t x[8];
      for (int p = 0; p < 8; ++p) x[p] = __shfl_xor((int)pk[p], 32);
      bool h1 = (half != 0);
      u32x4 f0 = {h1 ? x[2] : pk[0], h1 ? x[3] : pk[1],
                  h1 ? pk[2] : x[0], h1 ? pk[3] : x[1]};
      u32x4 f1 = {h1 ? x[6] : pk[4], h1 ? x[7] : pk[5],
                  h1 ? pk[6] : x[4], h1 ? pk[7] : x[5]};
      bf16x8 Fa = __builtin_bit_cast(bf16x8, f0);
      bf16x8 Fb = __builtin_bit_cast(bf16x8, f1);

      // O^T += V^T_tile · P^T_tile
      for (int hdt = 0; hdt < 2; ++hdt) {
        const int rowv = hdt * 32 + q31;
        int ch0 = (4 * st + half) ^ (rowv & 7);
        int ch1 = (4 * st + 2 + half) ^ (rowv & 7);
        bf16x8 fv0 = *(const bf16x8*)((const char*)&lV[cur][0] + rowv * 128 + ch0 * 16);
        bf16x8 fv1 = *(const bf16x8*)((const char*)&lV[cur][0] + rowv * 128 + ch1 * 16);
        o[hdt] = __builtin_amdgcn_mfma_f32_32x32x16_bf16(fv0, Fa, o[hdt], 0, 0, 0);
        o[hdt] = __builtin_amdgcn_mfma_f32_32x32x16_bf16(fv1, Fb, o[hdt], 0, 0, 0);
      }
    }
  }

  // store partials: po[(kc*32+bh)][qrow][hd] bf16 (packed 8B), pl fp32
  float ltot = lsum + __shfl_xor(lsum, 32);
  const size_t slab = (size_t)(kc * 32 + bh) * S_;
  const int qrow = q0w + q31;
  if (half == 0) pl[slab + qrow] = ltot;
  for (int hdt = 0; hdt < 2; ++hdt)
    for (int rq = 0; rq < 4; ++rq) {
      bf16x4 pk;
      pk[0] = (__bf16)o[hdt][rq * 4 + 0];
      pk[1] = (__bf16)o[hdt][rq * 4 + 1];
      pk[2] = (__bf16)o[hdt][rq * 4 + 2];
      pk[3] = (__bf16)o[hdt][rq * 4 + 3];
      *(bf16x4*)(po + (slab + qrow) * HD_ + hdt * 32 + rq * 8 + half * 4) = pk;
    }
}

// ---------------- attention phase 2: combine, divide, mean-pool ----------------
// grid (rg=32, bh=32) = 1024 blocks (4/CU). Each block: 64 rows x 2 slabs.
__global__ __launch_bounds__(256) void attn2(const __bf16* __restrict__ po,
                                             const float* __restrict__ pl,
                                             float* __restrict__ out) {
  __shared__ float red[256];
  const int t = threadIdx.x;
  const int hd = t & 63;
  const int rgrp = t >> 6;
  const int bh = blockIdx.y;
  const int r0 = blockIdx.x * 64 + rgrp * 16;
  const size_t s0 = (size_t)bh * S_;
  const size_t s1 = (size_t)(32 + bh) * S_;
  float acc = 0.f;
#pragma unroll 4
  for (int i = 0; i < 16; ++i) {
    int row = r0 + i;
    float l = pl[s0 + row] + pl[s1 + row];
    float v = (float)po[(s0 + row) * HD_ + hd] +
              (float)po[(s1 + row) * HD_ + hd];
    acc += v / l;
  }
  red[t] = acc;
  __syncthreads();
  if (t < 64) {
    float s = red[t] + red[t + 64] + red[t + 128] + red[t + 192];
    atomicAdd(out + (size_t)(bh >> 4) * D_ + (bh & 15) * HD_ + hd,
              s * (1.0f / S_));
  }
}

extern "C" void kernel_launch(void* const* d_in, const int* in_sizes, int n_in,
                              void* d_out, int out_size, void* d_ws, size_t ws_size,
                              hipStream_t stream) {
  const float* x  = (const float*)d_in[0];
  const float* Wq = (const float*)d_in[1];
  const float* bq = (const float*)d_in[2];
  const float* Wk = (const float*)d_in[3];
  const float* bk = (const float*)d_in[4];
  const float* Wv = (const float*)d_in[5];
  const float* bv = (const float*)d_in[6];
  float* out = (float*)d_out;

  char* ws = (char*)d_ws;
  __bf16* qh = (__bf16*)(ws);                       //  0..8 MB
  __bf16* kh = (__bf16*)(ws + ((size_t)8  << 20));  //  8..16 MB
  __bf16* vt = (__bf16*)(ws + ((size_t)16 << 20));  // 16..24 MB
  __bf16* xb = (__bf16*)(ws + ((size_t)24 << 20));  // 24..32 MB (dead after gemm)
  __bf16* wt = (__bf16*)(ws + ((size_t)32 << 20));  // 32..38 MB (dead after gemm)
  __bf16* po = (__bf16*)(ws + ((size_t)24 << 20));  // 24..40 MB (overlays xb/wt)
  float*  pl = (float*) (ws + ((size_t)40 << 20));  // 40..40.5 MB

  prep<<<dim3(7169), dim3(256), 0, stream>>>(x, Wq, Wk, Wv, xb, wt, out);
  gemm_qkv<<<dim3(32, 16, 3), dim3(256), 0, stream>>>(xb, wt, bq, bk, bv, qh, kh, vt);
  attn1<<<dim3(B_ * H_, S_ / 128, 2), dim3(256), 0, stream>>>(qh, kh, vt, po, pl);
  attn2<<<dim3(32, B_ * H_), dim3(256), 0, stream>>>(po, pl, out);
}

// Round 10
// 163.239 us; speedup vs baseline: 1.0870x; 1.0870x over previous
//
#include <hip/hip_runtime.h>
#include <hip/hip_bf16.h>
#include <stdint.h>

#define B_  2
#define S_  2048
#define D_  1024
#define H_  16
#define HD_ 64

typedef __attribute__((ext_vector_type(8)))  __bf16 bf16x8;
typedef __attribute__((ext_vector_type(4)))  __bf16 bf16x4;
typedef __attribute__((ext_vector_type(2)))  __bf16 bf16x2;
typedef __attribute__((ext_vector_type(4)))  short  s16x4;
typedef __attribute__((ext_vector_type(4)))  float  f32x4;
typedef __attribute__((ext_vector_type(16))) float  f32x16;
typedef __attribute__((ext_vector_type(2)))  uint32_t u32x2;

// 0.125 * log2(e): folded into Q so attention scores feed exp2 directly.
#define QSCALE 0.18033688011112042f

__device__ __forceinline__ void gload16(const void* g, void* l) {
  __builtin_amdgcn_global_load_lds(
      (__attribute__((address_space(1))) void*)(uintptr_t)g,
      (__attribute__((address_space(3))) void*)(uintptr_t)l,
      16, 0, 0);
}

// ---------------- fused prep: zero out / convert X / transpose W ----------------
__global__ __launch_bounds__(256) void prep(
    const float* __restrict__ x, const float* __restrict__ wq,
    const float* __restrict__ wk, const float* __restrict__ wv,
    __bf16* __restrict__ xb, __bf16* __restrict__ wt, float* __restrict__ out) {
  __shared__ float tile[32][33];
  const int t = threadIdx.x;
  const int bx = blockIdx.x;
  if (bx < 4096) {
    int i = bx * 256 + t;
    float4 v = ((const float4*)x)[i];
    bf16x4 o;
    o[0] = (__bf16)v.x; o[1] = (__bf16)v.y; o[2] = (__bf16)v.z; o[3] = (__bf16)v.w;
    ((bf16x4*)xb)[i] = o;
  } else if (bx < 7168) {
    int tb = bx - 4096;
    int z = tb >> 10;
    int rem = tb & 1023;
    int n0 = (rem & 31) * 32, k0 = (rem >> 5) * 32;
    const float* w = (z == 0) ? wq : (z == 1 ? wk : wv);
    __bf16* o = wt + (size_t)z * D_ * D_;
    int tx = t & 31, ty = t >> 5;
    for (int i = 0; i < 4; ++i)
      tile[ty + 8 * i][tx] = w[(size_t)(k0 + ty + 8 * i) * D_ + n0 + tx];
    __syncthreads();
    for (int i = 0; i < 4; ++i)
      o[(size_t)(n0 + ty + 8 * i) * D_ + k0 + tx] = (__bf16)tile[tx][ty + 8 * i];
  } else {
    float4* o4 = (float4*)out;
    float4 z4 = {0.f, 0.f, 0.f, 0.f};
    o4[t] = z4;
    o4[t + 256] = z4;
  }
}

// ---------------- QKV GEMM, 128x128, BK=32, dbuf (R5 version) ----------------
// grid (my=32, nx=8, z=3): same-A-panel blocks share XCD L2 (linear%8 = my%8).
__global__ __launch_bounds__(256, 3) void gemm_qkv(
    const __bf16* __restrict__ xb, const __bf16* __restrict__ wt,
    const float* __restrict__ bq, const float* __restrict__ bk,
    const float* __restrict__ bv, __bf16* __restrict__ qh,
    __bf16* __restrict__ kh, __bf16* __restrict__ vt) {
  constexpr int K = 1024;
  constexpr int NIT = K / 32;
  __shared__ __attribute__((aligned(16))) __bf16 lA[2][128 * 32];
  __shared__ __attribute__((aligned(16))) __bf16 lB[2][128 * 32];

  const int z = blockIdx.z;
  const __bf16* w = wt + (size_t)z * K * D_;
  const float* bias = (z == 0) ? bq : (z == 1 ? bk : bv);
  const int t = threadIdx.x;
  const int lane = t & 63;
  const int wid = t >> 6;
  const int quad = lane >> 4;
  const int col = lane & 15;
  const int m0 = blockIdx.x * 128;
  const int n0 = blockIdx.y * 128;
  const int wr = (wid >> 1) * 64;
  const int wc = (wid & 1) * 64;

  const int sr0 = t >> 2;
  const int gc = (t & 3) ^ ((t >> 2) & 3);

  auto stage = [&](int kt, int buf) {
    gload16(xb + (size_t)(m0 + sr0) * K + kt * 32 + gc * 8,
            (char*)&lA[buf][0] + t * 16);
    gload16(xb + (size_t)(m0 + 64 + sr0) * K + kt * 32 + gc * 8,
            (char*)&lA[buf][0] + 4096 + t * 16);
    gload16(w + (size_t)(n0 + sr0) * K + kt * 32 + gc * 8,
            (char*)&lB[buf][0] + t * 16);
    gload16(w + (size_t)(n0 + 64 + sr0) * K + kt * 32 + gc * 8,
            (char*)&lB[buf][0] + 4096 + t * 16);
  };

  f32x4 acc[4][4] = {};

  stage(0, 0);

  if (z < 2) {
    for (int kt = 0; kt < NIT; ++kt) {
      const int cur = kt & 1;
      __syncthreads();
      if (kt + 1 < NIT) stage(kt + 1, cur ^ 1);
      bf16x8 fw[4], fx[4];
      for (int i = 0; i < 4; ++i) {
        int n = wr + i * 16 + col;
        int sl = quad ^ (n & 3);
        fw[i] = *(const bf16x8*)((const char*)&lB[cur][0] + n * 64 + sl * 16);
      }
      for (int j = 0; j < 4; ++j) {
        int m = wc + j * 16 + col;
        int sl = quad ^ (m & 3);
        fx[j] = *(const bf16x8*)((const char*)&lA[cur][0] + m * 64 + sl * 16);
      }
      for (int i = 0; i < 4; ++i)
        for (int j = 0; j < 4; ++j)
          acc[i][j] = __builtin_amdgcn_mfma_f32_16x16x32_bf16(
              fw[i], fx[j], acc[i][j], 0, 0, 0);
    }
    const float scale = (z == 0) ? QSCALE : 1.0f;
    __bf16* dst = (z == 0) ? qh : kh;
    for (int i = 0; i < 4; ++i) {
      int gnb = n0 + wr + i * 16 + quad * 4;
      float4 bi = *(const float4*)(bias + gnb);
      int h = gnb >> 6, hd = gnb & 63;
      for (int j = 0; j < 4; ++j) {
        int gm = m0 + wc + j * 16 + col;
        int b = gm >> 11, s = gm & 2047;
        bf16x4 pk;
        pk[0] = (__bf16)((acc[i][j][0] + bi.x) * scale);
        pk[1] = (__bf16)((acc[i][j][1] + bi.y) * scale);
        pk[2] = (__bf16)((acc[i][j][2] + bi.z) * scale);
        pk[3] = (__bf16)((acc[i][j][3] + bi.w) * scale);
        *(bf16x4*)(dst + ((size_t)(b * H_ + h) * S_ + s) * HD_ + hd) = pk;
      }
    }
  } else {
    for (int kt = 0; kt < NIT; ++kt) {
      const int cur = kt & 1;
      __syncthreads();
      if (kt + 1 < NIT) stage(kt + 1, cur ^ 1);
      bf16x8 fx[4], fw[4];
      for (int i = 0; i < 4; ++i) {
        int m = wr + i * 16 + col;
        int sl = quad ^ (m & 3);
        fx[i] = *(const bf16x8*)((const char*)&lA[cur][0] + m * 64 + sl * 16);
      }
      for (int j = 0; j < 4; ++j) {
        int n = wc + j * 16 + col;
        int sl = quad ^ (n & 3);
        fw[j] = *(const bf16x8*)((const char*)&lB[cur][0] + n * 64 + sl * 16);
      }
      for (int i = 0; i < 4; ++i)
        for (int j = 0; j < 4; ++j)
          acc[i][j] = __builtin_amdgcn_mfma_f32_16x16x32_bf16(
              fx[i], fw[j], acc[i][j], 0, 0, 0);
    }
    for (int i = 0; i < 4; ++i) {
      int gmb = m0 + wr + i * 16 + quad * 4;
      int b = gmb >> 11, s = gmb & 2047;
      for (int j = 0; j < 4; ++j) {
        int gn = n0 + wc + j * 16 + col;
        int h = gn >> 6, hd = gn & 63;
        float bi = bias[gn];
        bf16x4 pk;
        pk[0] = (__bf16)(acc[i][j][0] + bi);
        pk[1] = (__bf16)(acc[i][j][1] + bi);
        pk[2] = (__bf16)(acc[i][j][2] + bi);
        pk[3] = (__bf16)(acc[i][j][3] + bi);
        *(bf16x4*)(vt + ((size_t)(b * H_ + h) * HD_ + hd) * S_ + s) = pk;
      }
    }
  }
}

// ---------------- attention phase 1: 64 q-rows/wave, shared K/V frags ----------------
// grid (bh=32, qblk=8, kc=2) = 512 blocks = 2/CU; XCD = bh%8.
// Each wave owns 64 q (2 q-tiles). Every fk/fv LDS read feeds BOTH q-tiles'
// MFMAs -> LDS-read traffic per unit work halves (it was the largest term).
// Dbuf K-tile=64 staging (R8); PV via K8 MFMA (no shfl, R8-proven).
__global__ __launch_bounds__(256, 2) void attn1(
    const __bf16* __restrict__ qh, const __bf16* __restrict__ kh,
    const __bf16* __restrict__ vt, __bf16* __restrict__ po,
    float* __restrict__ pl) {
  __shared__ __attribute__((aligned(16))) __bf16 lK[2][64 * 64];  // [sk][hd] swz
  __shared__ __attribute__((aligned(16))) __bf16 lV[2][64 * 64];  // [hd][sk] swz

  const int t = threadIdx.x;
  const int lane = t & 63;
  const int half = lane >> 5;
  const int q31 = lane & 31;
  const int bh = blockIdx.x;
  const int kc = blockIdx.z;
  const int q0w = blockIdx.y * 256 + (t >> 6) * 64;  // wave's 64 q rows

  const __bf16* qbase = qh + (size_t)bh * S_ * HD_;
  const __bf16* kbase = kh + (size_t)bh * S_ * HD_;
  const __bf16* vbase = vt + (size_t)bh * HD_ * S_;

  // Q as B-frags: B[n=q=lane&31][k=16ks+8*half+j], per q-tile
  bf16x8 aq[2][4];
  for (int qt = 0; qt < 2; ++qt)
    for (int ks = 0; ks < 4; ++ks)
      aq[qt][ks] = *(const bf16x8*)(qbase +
          (size_t)(q0w + qt * 32 + q31) * HD_ + ks * 16 + half * 8);

  f32x16 o[2][2] = {};  // [qt][hdt]
  float lsum[2] = {0.f, 0.f};

  const int srow = t >> 3;                  // 0..31
  const int sgc = (t & 7) ^ (srow & 7);     // swizzled global chunk

  auto stage = [&](int kt, int buf) {
    gload16(kbase + (size_t)(kt * 64 + srow) * HD_ + sgc * 8,
            (char*)&lK[buf][0] + t * 16);
    gload16(kbase + (size_t)(kt * 64 + 32 + srow) * HD_ + sgc * 8,
            (char*)&lK[buf][0] + 4096 + t * 16);
    gload16(vbase + (size_t)srow * S_ + kt * 64 + sgc * 8,
            (char*)&lV[buf][0] + t * 16);
    gload16(vbase + (size_t)(32 + srow) * S_ + kt * 64 + sgc * 8,
            (char*)&lV[buf][0] + 4096 + t * 16);
  };

  stage(kc * 16, 0);

  for (int kt0 = 0; kt0 < 16; ++kt0) {
    const int cur = kt0 & 1;
    __syncthreads();  // drains vmcnt: buf[cur] staged; all done reading buf[cur^1]
    if (kt0 + 1 < 16) stage(kc * 16 + kt0 + 1, cur ^ 1);

    for (int st = 0; st < 2; ++st) {
      // S^T tiles for both q-tiles; each fk load feeds two MFMAs
      f32x16 sc0 = {}, sc1 = {};
      const int row = st * 32 + q31;
      for (int ks = 0; ks < 4; ++ks) {
        int pos = (2 * ks + half) ^ (row & 7);
        bf16x8 fk = *(const bf16x8*)((const char*)&lK[cur][0] + row * 128 + pos * 16);
        sc0 = __builtin_amdgcn_mfma_f32_32x32x16_bf16(fk, aq[0][ks], sc0, 0, 0, 0);
        sc1 = __builtin_amdgcn_mfma_f32_32x32x16_bf16(fk, aq[1][ks], sc1, 0, 0, 0);
      }

      // exp2 + lsum + pack pairs via v_perm (round-half-up), per q-tile
      uint32_t pk0[8], pk1[8];
      for (int p = 0; p < 8; ++p) {
        float ea = __builtin_amdgcn_exp2f(sc0[2 * p]);
        float eb = __builtin_amdgcn_exp2f(sc0[2 * p + 1]);
        lsum[0] += ea;
        lsum[0] += eb;
        uint32_t au = __builtin_bit_cast(uint32_t, ea) + 0x8000u;
        uint32_t bu = __builtin_bit_cast(uint32_t, eb) + 0x8000u;
        pk0[p] = __builtin_amdgcn_perm(bu, au, 0x07060302u);
      }
      for (int p = 0; p < 8; ++p) {
        float ea = __builtin_amdgcn_exp2f(sc1[2 * p]);
        float eb = __builtin_amdgcn_exp2f(sc1[2 * p + 1]);
        lsum[1] += ea;
        lsum[1] += eb;
        uint32_t au = __builtin_bit_cast(uint32_t, ea) + 0x8000u;
        uint32_t bu = __builtin_bit_cast(uint32_t, eb) + 0x8000u;
        pk1[p] = __builtin_amdgcn_perm(bu, au, 0x07060302u);
      }

      // O^T += V^T · P^T via K=8 steps; each fv load feeds both q-tiles.
      // P-frag(qt,g) = regs {pk[2g], pk[2g+1]} (C-layout quads ARE the K8 frag)
      for (int hdt = 0; hdt < 2; ++hdt) {
        const int rowv = hdt * 32 + q31;
        for (int g = 0; g < 4; ++g) {
          int pos = (4 * st + g) ^ (rowv & 7);
          s16x4 fv = *(const s16x4*)((const char*)&lV[cur][0] + rowv * 128 +
                                     pos * 16 + half * 8);
          u32x2 fp0u = {pk0[2 * g], pk0[2 * g + 1]};
          u32x2 fp1u = {pk1[2 * g], pk1[2 * g + 1]};
          o[0][hdt] = __builtin_amdgcn_mfma_f32_32x32x8bf16_1k(
              fv, __builtin_bit_cast(s16x4, fp0u), o[0][hdt], 0, 0, 0);
          o[1][hdt] = __builtin_amdgcn_mfma_f32_32x32x8bf16_1k(
              fv, __builtin_bit_cast(s16x4, fp1u), o[1][hdt], 0, 0, 0);
        }
      }
    }
  }

  // store partials per q-tile: po[(kc*32+bh)][qrow][hd] bf16 (8B), pl fp32
  const size_t slab = (size_t)(kc * 32 + bh) * S_;
  for (int qt = 0; qt < 2; ++qt) {
    float ltot = lsum[qt] + __shfl_xor(lsum[qt], 32);
    const int qrow = q0w + qt * 32 + q31;
    if (half == 0) pl[slab + qrow] = ltot;
    for (int hdt = 0; hdt < 2; ++hdt)
      for (int rq = 0; rq < 4; ++rq) {
        bf16x4 pk;
        pk[0] = (__bf16)o[qt][hdt][rq * 4 + 0];
        pk[1] = (__bf16)o[qt][hdt][rq * 4 + 1];
        pk[2] = (__bf16)o[qt][hdt][rq * 4 + 2];
        pk[3] = (__bf16)o[qt][hdt][rq * 4 + 3];
        *(bf16x4*)(po + (slab + qrow) * HD_ + hdt * 32 + rq * 8 + half * 4) = pk;
      }
  }
}

// ---------------- attention phase 2: combine, divide, mean-pool ----------------
// grid (rg=32, bh=32) = 1024 blocks (4/CU). Each block: 64 rows x 2 slabs.
__global__ __launch_bounds__(256) void attn2(const __bf16* __restrict__ po,
                                             const float* __restrict__ pl,
                                             float* __restrict__ out) {
  __shared__ float red[256];
  const int t = threadIdx.x;
  const int hd = t & 63;
  const int rgrp = t >> 6;
  const int bh = blockIdx.y;
  const int r0 = blockIdx.x * 64 + rgrp * 16;
  const size_t s0 = (size_t)bh * S_;
  const size_t s1 = (size_t)(32 + bh) * S_;
  float acc = 0.f;
#pragma unroll 4
  for (int i = 0; i < 16; ++i) {
    int row = r0 + i;
    float l = pl[s0 + row] + pl[s1 + row];
    float v = (float)po[(s0 + row) * HD_ + hd] +
              (float)po[(s1 + row) * HD_ + hd];
    acc += v / l;
  }
  red[t] = acc;
  __syncthreads();
  if (t < 64) {
    float s = red[t] + red[t + 64] + red[t + 128] + red[t + 192];
    atomicAdd(out + (size_t)(bh >> 4) * D_ + (bh & 15) * HD_ + hd,
              s * (1.0f / S_));
  }
}

extern "C" void kernel_launch(void* const* d_in, const int* in_sizes, int n_in,
                              void* d_out, int out_size, void* d_ws, size_t ws_size,
                              hipStream_t stream) {
  const float* x  = (const float*)d_in[0];
  const float* Wq = (const float*)d_in[1];
  const float* bq = (const float*)d_in[2];
  const float* Wk = (const float*)d_in[3];
  const float* bk = (const float*)d_in[4];
  const float* Wv = (const float*)d_in[5];
  const float* bv = (const float*)d_in[6];
  float* out = (float*)d_out;

  char* ws = (char*)d_ws;
  __bf16* qh = (__bf16*)(ws);                       //  0..8 MB
  __bf16* kh = (__bf16*)(ws + ((size_t)8  << 20));  //  8..16 MB
  __bf16* vt = (__bf16*)(ws + ((size_t)16 << 20));  // 16..24 MB
  __bf16* xb = (__bf16*)(ws + ((size_t)24 << 20));  // 24..32 MB (dead after gemm)
  __bf16* wt = (__bf16*)(ws + ((size_t)32 << 20));  // 32..38 MB (dead after gemm)
  __bf16* po = (__bf16*)(ws + ((size_t)24 << 20));  // 24..40 MB (overlays xb/wt)
  float*  pl = (float*) (ws + ((size_t)40 << 20));  // 40..40.5 MB

  prep<<<dim3(7169), dim3(256), 0, stream>>>(x, Wq, Wk, Wv, xb, wt, out);
  gemm_qkv<<<dim3(32, 8, 3), dim3(256), 0, stream>>>(xb, wt, bq, bk, bv, qh, kh, vt);
  attn1<<<dim3(B_ * H_, 8, 2), dim3(256), 0, stream>>>(qh, kh, vt, po, pl);
  attn2<<<dim3(32, B_ * H_), dim3(256), 0, stream>>>(po, pl, out);
}

// Round 12
// 160.894 us; speedup vs baseline: 1.1028x; 1.0146x over previous
//
#include <hip/hip_runtime.h>
#include <hip/hip_bf16.h>
#include <stdint.h>

#define B_  2
#define S_  2048
#define D_  1024
#define H_  16
#define HD_ 64

typedef __attribute__((ext_vector_type(8)))  __bf16 bf16x8;
typedef __attribute__((ext_vector_type(4)))  __bf16 bf16x4;
typedef __attribute__((ext_vector_type(2)))  __bf16 bf16x2;
typedef __attribute__((ext_vector_type(4)))  short  s16x4;
typedef __attribute__((ext_vector_type(4)))  float  f32x4;
typedef __attribute__((ext_vector_type(16))) float  f32x16;
typedef __attribute__((ext_vector_type(2)))  uint32_t u32x2;

// 0.125 * log2(e): folded into Q so attention scores feed exp2 directly.
#define QSCALE 0.18033688011112042f

__device__ __forceinline__ void gload16(const void* g, void* l) {
  __builtin_amdgcn_global_load_lds(
      (__attribute__((address_space(1))) void*)(uintptr_t)g,
      (__attribute__((address_space(3))) void*)(uintptr_t)l,
      16, 0, 0);
}

// ---------------- fused prep: zero out / convert X / transpose W ----------------
__global__ __launch_bounds__(256) void prep(
    const float* __restrict__ x, const float* __restrict__ wq,
    const float* __restrict__ wk, const float* __restrict__ wv,
    __bf16* __restrict__ xb, __bf16* __restrict__ wt, float* __restrict__ out) {
  __shared__ float tile[32][33];
  const int t = threadIdx.x;
  const int bx = blockIdx.x;
  if (bx < 4096) {
    int i = bx * 256 + t;
    float4 v = ((const float4*)x)[i];
    bf16x4 o;
    o[0] = (__bf16)v.x; o[1] = (__bf16)v.y; o[2] = (__bf16)v.z; o[3] = (__bf16)v.w;
    ((bf16x4*)xb)[i] = o;
  } else if (bx < 7168) {
    int tb = bx - 4096;
    int z = tb >> 10;
    int rem = tb & 1023;
    int n0 = (rem & 31) * 32, k0 = (rem >> 5) * 32;
    const float* w = (z == 0) ? wq : (z == 1 ? wk : wv);
    __bf16* o = wt + (size_t)z * D_ * D_;
    int tx = t & 31, ty = t >> 5;
    for (int i = 0; i < 4; ++i)
      tile[ty + 8 * i][tx] = w[(size_t)(k0 + ty + 8 * i) * D_ + n0 + tx];
    __syncthreads();
    for (int i = 0; i < 4; ++i)
      o[(size_t)(n0 + ty + 8 * i) * D_ + k0 + tx] = (__bf16)tile[tx][ty + 8 * i];
  } else {
    float4* o4 = (float4*)out;
    float4 z4 = {0.f, 0.f, 0.f, 0.f};
    o4[t] = z4;
    o4[t + 256] = z4;
  }
}

// ---------------- QKV GEMM, 128x128, BK=32, dbuf (R5/R10 version) ----------------
// grid (my=32, nx=8, z=3): same-A-panel blocks share XCD L2 (linear%8 = my%8).
__global__ __launch_bounds__(256, 3) void gemm_qkv(
    const __bf16* __restrict__ xb, const __bf16* __restrict__ wt,
    const float* __restrict__ bq, const float* __restrict__ bk,
    const float* __restrict__ bv, __bf16* __restrict__ qh,
    __bf16* __restrict__ kh, __bf16* __restrict__ vt) {
  constexpr int K = 1024;
  constexpr int NIT = K / 32;
  __shared__ __attribute__((aligned(16))) __bf16 lA[2][128 * 32];
  __shared__ __attribute__((aligned(16))) __bf16 lB[2][128 * 32];

  const int z = blockIdx.z;
  const __bf16* w = wt + (size_t)z * K * D_;
  const float* bias = (z == 0) ? bq : (z == 1 ? bk : bv);
  const int t = threadIdx.x;
  const int lane = t & 63;
  const int wid = t >> 6;
  const int quad = lane >> 4;
  const int col = lane & 15;
  const int m0 = blockIdx.x * 128;
  const int n0 = blockIdx.y * 128;
  const int wr = (wid >> 1) * 64;
  const int wc = (wid & 1) * 64;

  const int sr0 = t >> 2;
  const int gc = (t & 3) ^ ((t >> 2) & 3);

  auto stage = [&](int kt, int buf) {
    gload16(xb + (size_t)(m0 + sr0) * K + kt * 32 + gc * 8,
            (char*)&lA[buf][0] + t * 16);
    gload16(xb + (size_t)(m0 + 64 + sr0) * K + kt * 32 + gc * 8,
            (char*)&lA[buf][0] + 4096 + t * 16);
    gload16(w + (size_t)(n0 + sr0) * K + kt * 32 + gc * 8,
            (char*)&lB[buf][0] + t * 16);
    gload16(w + (size_t)(n0 + 64 + sr0) * K + kt * 32 + gc * 8,
            (char*)&lB[buf][0] + 4096 + t * 16);
  };

  f32x4 acc[4][4] = {};

  stage(0, 0);

  if (z < 2) {
    for (int kt = 0; kt < NIT; ++kt) {
      const int cur = kt & 1;
      __syncthreads();
      if (kt + 1 < NIT) stage(kt + 1, cur ^ 1);
      bf16x8 fw[4], fx[4];
      for (int i = 0; i < 4; ++i) {
        int n = wr + i * 16 + col;
        int sl = quad ^ (n & 3);
        fw[i] = *(const bf16x8*)((const char*)&lB[cur][0] + n * 64 + sl * 16);
      }
      for (int j = 0; j < 4; ++j) {
        int m = wc + j * 16 + col;
        int sl = quad ^ (m & 3);
        fx[j] = *(const bf16x8*)((const char*)&lA[cur][0] + m * 64 + sl * 16);
      }
      for (int i = 0; i < 4; ++i)
        for (int j = 0; j < 4; ++j)
          acc[i][j] = __builtin_amdgcn_mfma_f32_16x16x32_bf16(
              fw[i], fx[j], acc[i][j], 0, 0, 0);
    }
    const float scale = (z == 0) ? QSCALE : 1.0f;
    __bf16* dst = (z == 0) ? qh : kh;
    for (int i = 0; i < 4; ++i) {
      int gnb = n0 + wr + i * 16 + quad * 4;
      float4 bi = *(const float4*)(bias + gnb);
      int h = gnb >> 6, hd = gnb & 63;
      for (int j = 0; j < 4; ++j) {
        int gm = m0 + wc + j * 16 + col;
        int b = gm >> 11, s = gm & 2047;
        bf16x4 pk;
        pk[0] = (__bf16)((acc[i][j][0] + bi.x) * scale);
        pk[1] = (__bf16)((acc[i][j][1] + bi.y) * scale);
        pk[2] = (__bf16)((acc[i][j][2] + bi.z) * scale);
        pk[3] = (__bf16)((acc[i][j][3] + bi.w) * scale);
        *(bf16x4*)(dst + ((size_t)(b * H_ + h) * S_ + s) * HD_ + hd) = pk;
      }
    }
  } else {
    for (int kt = 0; kt < NIT; ++kt) {
      const int cur = kt & 1;
      __syncthreads();
      if (kt + 1 < NIT) stage(kt + 1, cur ^ 1);
      bf16x8 fx[4], fw[4];
      for (int i = 0; i < 4; ++i) {
        int m = wr + i * 16 + col;
        int sl = quad ^ (m & 3);
        fx[i] = *(const bf16x8*)((const char*)&lA[cur][0] + m * 64 + sl * 16);
      }
      for (int j = 0; j < 4; ++j) {
        int n = wc + j * 16 + col;
        int sl = quad ^ (n & 3);
        fw[j] = *(const bf16x8*)((const char*)&lB[cur][0] + n * 64 + sl * 16);
      }
      for (int i = 0; i < 4; ++i)
        for (int j = 0; j < 4; ++j)
          acc[i][j] = __builtin_amdgcn_mfma_f32_16x16x32_bf16(
              fx[i], fw[j], acc[i][j], 0, 0, 0);
    }
    for (int i = 0; i < 4; ++i) {
      int gmb = m0 + wr + i * 16 + quad * 4;
      int b = gmb >> 11, s = gmb & 2047;
      for (int j = 0; j < 4; ++j) {
        int gn = n0 + wc + j * 16 + col;
        int h = gn >> 6, hd = gn & 63;
        float bi = bias[gn];
        bf16x4 pk;
        pk[0] = (__bf16)(acc[i][j][0] + bi);
        pk[1] = (__bf16)(acc[i][j][1] + bi);
        pk[2] = (__bf16)(acc[i][j][2] + bi);
        pk[3] = (__bf16)(acc[i][j][3] + bi);
        *(bf16x4*)(vt + ((size_t)(b * H_ + h) * HD_ + hd) * S_ + s) = pk;
      }
    }
  }
}

// ---------------- attention phase 1: 64 q/wave, hoisted LDS reads ----------------
// grid (bh=32, qblk=8, kc=2) = 512 blocks = 2/CU; XCD = bh%8.
// R10 structure; change: ALL ds_reads (fk x8 b128, fv x16 b64) issue at the
// top of each K-iteration into registers, 300+ cyc before first use, so the
// ~120-cyc LDS latency is off the QK->exp->PV critical path.
__global__ __launch_bounds__(256, 2) void attn1(
    const __bf16* __restrict__ qh, const __bf16* __restrict__ kh,
    const __bf16* __restrict__ vt, __bf16* __restrict__ po,
    float* __restrict__ pl) {
  __shared__ __attribute__((aligned(16))) __bf16 lK[2][64 * 64];  // [sk][hd] swz
  __shared__ __attribute__((aligned(16))) __bf16 lV[2][64 * 64];  // [hd][sk] swz

  const int t = threadIdx.x;
  const int lane = t & 63;
  const int half = lane >> 5;
  const int q31 = lane & 31;
  const int bh = blockIdx.x;
  const int kc = blockIdx.z;
  const int q0w = blockIdx.y * 256 + (t >> 6) * 64;  // wave's 64 q rows

  const __bf16* qbase = qh + (size_t)bh * S_ * HD_;
  const __bf16* kbase = kh + (size_t)bh * S_ * HD_;
  const __bf16* vbase = vt + (size_t)bh * HD_ * S_;

  // Q as B-frags: B[n=q=lane&31][k=16ks+8*half+j], per q-tile
  bf16x8 aq[2][4];
  for (int qt = 0; qt < 2; ++qt)
    for (int ks = 0; ks < 4; ++ks)
      aq[qt][ks] = *(const bf16x8*)(qbase +
          (size_t)(q0w + qt * 32 + q31) * HD_ + ks * 16 + half * 8);

  f32x16 o[2][2] = {};  // [qt][hdt]
  float lsum[2] = {0.f, 0.f};

  const int srow = t >> 3;                  // 0..31
  const int sgc = (t & 7) ^ (srow & 7);     // swizzled global chunk

  auto stage = [&](int kt, int buf) {
    gload16(kbase + (size_t)(kt * 64 + srow) * HD_ + sgc * 8,
            (char*)&lK[buf][0] + t * 16);
    gload16(kbase + (size_t)(kt * 64 + 32 + srow) * HD_ + sgc * 8,
            (char*)&lK[buf][0] + 4096 + t * 16);
    gload16(vbase + (size_t)srow * S_ + kt * 64 + sgc * 8,
            (char*)&lV[buf][0] + t * 16);
    gload16(vbase + (size_t)(32 + srow) * S_ + kt * 64 + sgc * 8,
            (char*)&lV[buf][0] + 4096 + t * 16);
  };

  stage(kc * 16, 0);

  for (int kt0 = 0; kt0 < 16; ++kt0) {
    const int cur = kt0 & 1;
    __syncthreads();  // drains vmcnt: buf[cur] staged; all done reading buf[cur^1]
    if (kt0 + 1 < 16) stage(kc * 16 + kt0 + 1, cur ^ 1);

    // ---- hoisted LDS reads: everything this iteration needs ----
    bf16x8 fk[2][4];       // [st][ks]
    s16x4  fv[2][2][4];    // [st][hdt][g]
#pragma unroll
    for (int st = 0; st < 2; ++st) {
      const int row = st * 32 + q31;
#pragma unroll
      for (int ks = 0; ks < 4; ++ks) {
        int pos = (2 * ks + half) ^ (row & 7);
        fk[st][ks] = *(const bf16x8*)((const char*)&lK[cur][0] + row * 128 + pos * 16);
      }
    }
#pragma unroll
    for (int st = 0; st < 2; ++st)
#pragma unroll
      for (int hdt = 0; hdt < 2; ++hdt) {
        const int rowv = hdt * 32 + q31;
#pragma unroll
        for (int g = 0; g < 4; ++g) {
          int pos = (4 * st + g) ^ (rowv & 7);
          fv[st][hdt][g] = *(const s16x4*)((const char*)&lV[cur][0] + rowv * 128 +
                                           pos * 16 + half * 8);
        }
      }

#pragma unroll
    for (int st = 0; st < 2; ++st) {
      // S^T tiles for both q-tiles; each fk feeds two MFMAs
      f32x16 sc0 = {}, sc1 = {};
#pragma unroll
      for (int ks = 0; ks < 4; ++ks) {
        sc0 = __builtin_amdgcn_mfma_f32_32x32x16_bf16(fk[st][ks], aq[0][ks], sc0, 0, 0, 0);
        sc1 = __builtin_amdgcn_mfma_f32_32x32x16_bf16(fk[st][ks], aq[1][ks], sc1, 0, 0, 0);
      }

      // exp2 + lsum + pack pairs via v_perm (round-half-up), per q-tile
      uint32_t pk0[8], pk1[8];
#pragma unroll
      for (int p = 0; p < 8; ++p) {
        float ea = __builtin_amdgcn_exp2f(sc0[2 * p]);
        float eb = __builtin_amdgcn_exp2f(sc0[2 * p + 1]);
        lsum[0] += ea;
        lsum[0] += eb;
        uint32_t au = __builtin_bit_cast(uint32_t, ea) + 0x8000u;
        uint32_t bu = __builtin_bit_cast(uint32_t, eb) + 0x8000u;
        pk0[p] = __builtin_amdgcn_perm(bu, au, 0x07060302u);
      }
#pragma unroll
      for (int p = 0; p < 8; ++p) {
        float ea = __builtin_amdgcn_exp2f(sc1[2 * p]);
        float eb = __builtin_amdgcn_exp2f(sc1[2 * p + 1]);
        lsum[1] += ea;
        lsum[1] += eb;
        uint32_t au = __builtin_bit_cast(uint32_t, ea) + 0x8000u;
        uint32_t bu = __builtin_bit_cast(uint32_t, eb) + 0x8000u;
        pk1[p] = __builtin_amdgcn_perm(bu, au, 0x07060302u);
      }

      // O^T += V^T · P^T via K=8 steps; each fv feeds both q-tiles
#pragma unroll
      for (int hdt = 0; hdt < 2; ++hdt) {
#pragma unroll
        for (int g = 0; g < 4; ++g) {
          u32x2 fp0u = {pk0[2 * g], pk0[2 * g + 1]};
          u32x2 fp1u = {pk1[2 * g], pk1[2 * g + 1]};
          o[0][hdt] = __builtin_amdgcn_mfma_f32_32x32x8bf16_1k(
              fv[st][hdt][g], __builtin_bit_cast(s16x4, fp0u), o[0][hdt], 0, 0, 0);
          o[1][hdt] = __builtin_amdgcn_mfma_f32_32x32x8bf16_1k(
              fv[st][hdt][g], __builtin_bit_cast(s16x4, fp1u), o[1][hdt], 0, 0, 0);
        }
      }
    }
  }

  // store partials per q-tile: po[(kc*32+bh)][qrow][hd] bf16 (8B), pl fp32
  const size_t slab = (size_t)(kc * 32 + bh) * S_;
  for (int qt = 0; qt < 2; ++qt) {
    float ltot = lsum[qt] + __shfl_xor(lsum[qt], 32);
    const int qrow = q0w + qt * 32 + q31;
    if (half == 0) pl[slab + qrow] = ltot;
    for (int hdt = 0; hdt < 2; ++hdt)
      for (int rq = 0; rq < 4; ++rq) {
        bf16x4 pk;
        pk[0] = (__bf16)o[qt][hdt][rq * 4 + 0];
        pk[1] = (__bf16)o[qt][hdt][rq * 4 + 1];
        pk[2] = (__bf16)o[qt][hdt][rq * 4 + 2];
        pk[3] = (__bf16)o[qt][hdt][rq * 4 + 3];
        *(bf16x4*)(po + (slab + qrow) * HD_ + hdt * 32 + rq * 8 + half * 4) = pk;
      }
  }
}

// ---------------- attention phase 2: combine, divide, mean-pool ----------------
// grid (rg=32, bh=32) = 1024 blocks (4/CU). Each block: 64 rows x 2 slabs.
__global__ __launch_bounds__(256) void attn2(const __bf16* __restrict__ po,
                                             const float* __restrict__ pl,
                                             float* __restrict__ out) {
  __shared__ float red[256];
  const int t = threadIdx.x;
  const int hd = t & 63;
  const int rgrp = t >> 6;
  const int bh = blockIdx.y;
  const int r0 = blockIdx.x * 64 + rgrp * 16;
  const size_t s0 = (size_t)bh * S_;
  const size_t s1 = (size_t)(32 + bh) * S_;
  float acc = 0.f;
#pragma unroll 4
  for (int i = 0; i < 16; ++i) {
    int row = r0 + i;
    float l = pl[s0 + row] + pl[s1 + row];
    float v = (float)po[(s0 + row) * HD_ + hd] +
              (float)po[(s1 + row) * HD_ + hd];
    acc += v / l;
  }
  red[t] = acc;
  __syncthreads();
  if (t < 64) {
    float s = red[t] + red[t + 64] + red[t + 128] + red[t + 192];
    atomicAdd(out + (size_t)(bh >> 4) * D_ + (bh & 15) * HD_ + hd,
              s * (1.0f / S_));
  }
}

extern "C" void kernel_launch(void* const* d_in, const int* in_sizes, int n_in,
                              void* d_out, int out_size, void* d_ws, size_t ws_size,
                              hipStream_t stream) {
  const float* x  = (const float*)d_in[0];
  const float* Wq = (const float*)d_in[1];
  const float* bq = (const float*)d_in[2];
  const float* Wk = (const float*)d_in[3];
  const float* bk = (const float*)d_in[4];
  const float* Wv = (const float*)d_in[5];
  const float* bv = (const float*)d_in[6];
  float* out = (float*)d_out;

  char* ws = (char*)d_ws;
  __bf16* qh = (__bf16*)(ws);                       //  0..8 MB
  __bf16* kh = (__bf16*)(ws + ((size_t)8  << 20));  //  8..16 MB
  __bf16* vt = (__bf16*)(ws + ((size_t)16 << 20));  // 16..24 MB
  __bf16* xb = (__bf16*)(ws + ((size_t)24 << 20));  // 24..32 MB (dead after gemm)
  __bf16* wt = (__bf16*)(ws + ((size_t)32 << 20));  // 32..38 MB (dead after gemm)
  __bf16* po = (__bf16*)(ws + ((size_t)24 << 20));  // 24..40 MB (overlays xb/wt)
  float*  pl = (float*) (ws + ((size_t)40 << 20));  // 40..40.5 MB

  prep<<<dim3(7169), dim3(256), 0, stream>>>(x, Wq, Wk, Wv, xb, wt, out);
  gemm_qkv<<<dim3(32, 8, 3), dim3(256), 0, stream>>>(xb, wt, bq, bk, bv, qh, kh, vt);
  attn1<<<dim3(B_ * H_, 8, 2), dim3(256), 0, stream>>>(qh, kh, vt, po, pl);
  attn2<<<dim3(32, B_ * H_), dim3(256), 0, stream>>>(po, pl, out);
}